// Round 17
// baseline (4426.787 us; speedup 1.0000x reference)
//
#include <hip/hip_runtime.h>

// ---------------------------------------------------------------------------
// LSTM autoregressive, MI355X. Round 16 = r13 MINUS pacing (isolating whether
// the r10 FETCH collapse was spill-elimination, not lockstep), PLUS parallel
// head2 (512 thr, shfl reduce) from r15.
//  - BM=32, 256 blocks x 512 thr, launch_bounds(512,2) [proven zero-spill]
//  - LDS h0/h1/x double buffers: enc 2 barriers/step, dec 5
//  - weights: hi-only fp16 B, streamed 1-deep from L2 (864KB total, should
//    stay L2-resident with zero spill traffic)
// ---------------------------------------------------------------------------

typedef _Float16 f16;
typedef _Float16 f16x4 __attribute__((ext_vector_type(4)));
typedef _Float16 f16x8 __attribute__((ext_vector_type(8)));
typedef float    f32x4 __attribute__((ext_vector_type(4)));

#define MFMA16(a,b,c) __builtin_amdgcn_mfma_f32_16x16x32_f16((a),(b),(c),0,0,0)

#define BM 32
#define NBLK 256

// ws layout: fp16 B-hi fragments (halves), then fp32 region (floats)
#define HOFF_E0 0
#define HOFF_E1 81920
#define HOFF_D0 212992
#define HOFF_D1 294912
#define HOFF_H  425984
#define H_TOTAL 442368
#define FOFF    221184
#define FB_E0 0
#define FB_E1 512
#define FB_D0 1024
#define FB_D1 1536
#define FB_H1 2048
#define FB_W2 2176
#define FB_B2 2432
#define F_TOTAL 2434

#define HS 140    // h row stride (halves): 70 dw, 2-way free
#define XS 36     // x row stride (halves)
#define O1S 133   // o1 row stride (floats)

// LDS base offsets in halves; parity buffer at base + c*{HBUF,XBUF}
#define HBUF 4480         // 32*HS
#define XBUF 1152         // 32*XS
#define L_H0H 0           // +c*HBUF
#define L_H0L 8960
#define L_H1H 17920
#define L_H1L 26880
#define L_XH  35840       // +c*XBUF
#define L_XL  38144
#define L_HALVES 40448
#define LDS_BYTES 97920   // 80896 + 32*133*4

__device__ __forceinline__ float fsig(float x){ return 1.0f/(1.0f+__expf(-x)); }
__device__ __forceinline__ float ftanh(float x){
  float a = fabsf(x);
  float e = __expf(-2.0f*a);
  float t = (1.0f-e)/(1.0f+e);
  return x < 0.0f ? -t : t;
}

// A fragment: row = m*16 + (lane&15); k = kc + (lane>>4)*4 + j (+16 for j>=4)
template<int STRIDE>
__device__ __forceinline__ f16x8 load_afrag(const f16* buf, int m, int kc, int lane){
  const f16* p = buf + (m*16 + (lane&15))*STRIDE + kc + ((lane>>4)<<2);
  f16x4 lo = *(const f16x4*)p;
  f16x4 hi = *(const f16x4*)(p+16);
  return __builtin_shufflevector(lo, hi, 0,1,2,3,4,5,6,7);
}

__device__ __forceinline__ void init_acc(f32x4 acc[2][4],
                                         const float* __restrict__ bias, int wv, int lane){
#pragma unroll
  for (int i=0;i<4;++i){
    float bv = bias[wv*64 + i*16 + (lane&15)];
    f32x4 b4 = {bv,bv,bv,bv};
    acc[0][i]=b4; acc[1][i]=b4;
  }
}

// gates[32 rows][wave's 64 cols] += [A(SPLIT kt, HS) | C(rest, SB)] * B_hi
template<int KT, int SPLIT, int SB>
__device__ __forceinline__ void gemm2(f32x4 acc[2][4],
    const f16x8* __restrict__ Bp,
    const f16* __restrict__ Ah, const f16* __restrict__ Al,
    const f16* __restrict__ Ch, const f16* __restrict__ Cl,
    int wv, int lane)
{
  const int nb = wv*4;
  f16x8 Bc[4], Bn[4];
#pragma unroll
  for (int i=0;i<4;++i) Bc[i] = Bp[(nb + i)*64 + lane];
#pragma unroll
  for (int kt=0; kt<KT; ++kt){
    if (kt+1 < KT){
#pragma unroll
      for (int i=0;i<4;++i) Bn[i] = Bp[((kt+1)*32 + nb + i)*64 + lane];
    }
    f16x8 a0h,a0l,a1h,a1l;
    if (kt < SPLIT){
      int kc = kt*32;
      a0h = load_afrag<HS>(Ah, 0, kc, lane);
      a0l = load_afrag<HS>(Al, 0, kc, lane);
      a1h = load_afrag<HS>(Ah, 1, kc, lane);
      a1l = load_afrag<HS>(Al, 1, kc, lane);
    } else {
      int kc = (kt-SPLIT)*32;
      a0h = load_afrag<SB>(Ch, 0, kc, lane);
      a0l = load_afrag<SB>(Cl, 0, kc, lane);
      a1h = load_afrag<SB>(Ch, 1, kc, lane);
      a1l = load_afrag<SB>(Cl, 1, kc, lane);
    }
#pragma unroll
    for (int i=0;i<4;++i){
      acc[0][i] = MFMA16(a0h, Bc[i], acc[0][i]);
      acc[1][i] = MFMA16(a1h, Bc[i], acc[1][i]);
      acc[0][i] = MFMA16(a0l, Bc[i], acc[0][i]);
      acc[1][i] = MFMA16(a1l, Bc[i], acc[1][i]);
    }
#pragma unroll
    for (int i=0;i<4;++i) Bc[i] = Bn[i];
  }
}

// 4x4 transpose within a lane-quad
__device__ __forceinline__ void quad_transpose(float&a0,float&a1,float&a2,float&a3,int q){
  bool odd = (q & 1) != 0;
  float s0 = odd ? a0 : a1, s1 = odd ? a2 : a3;
  float r0 = __shfl_xor(s0,1), r1 = __shfl_xor(s1,1);
  float b0 = odd ? r0 : a0, b1 = odd ? a1 : r0;
  float b2 = odd ? r1 : a2, b3 = odd ? a3 : r1;
  bool hi = (q & 2) != 0;
  float u0 = hi ? b0 : b2, u1 = hi ? b1 : b3;
  float v0 = __shfl_xor(u0,2), v1 = __shfl_xor(u1,2);
  a0 = hi ? v0 : b0; a1 = hi ? v1 : b1;
  a2 = hi ? b2 : v0; a3 = hi ? b3 : v1;
}

__device__ __forceinline__ void lstm_update_m(f32x4 acc[2][4], float cr[2][4],
    f16* __restrict__ Dh, f16* __restrict__ Dl, int wv, int lane)
{
  const int q = lane & 3;
  const int rsub = ((lane>>4)<<2) + q;
  const int usub = wv*16 + ((lane&15)>>2);
#pragma unroll
  for (int mt=0;mt<2;++mt)
#pragma unroll
  for (int nt=0;nt<4;++nt){
    float a0=acc[mt][nt][0], a1=acc[mt][nt][1], a2=acc[mt][nt][2], a3=acc[mt][nt][3];
    quad_transpose(a0,a1,a2,a3,q);
    float iv=fsig(a0), fv=fsig(a1), gv=ftanh(a2), ov=fsig(a3);
    float cn = fv*cr[mt][nt] + iv*gv;
    cr[mt][nt] = cn;
    float h = ov*ftanh(cn);
    f16 hh = (f16)h;
    f16 hl = (f16)(h - (float)hh);
    int off = (mt*16 + rsub)*HS + usub + nt*4;
    Dh[off]=hh; Dl[off]=hl;
  }
}

__global__ void __launch_bounds__(512, 2)
lstm_main(const float* __restrict__ hist, float* __restrict__ ws,
          float* __restrict__ out)
{
  const f16* wh = (const f16*)ws;
  const float* wf = ws + FOFF;
  const f16x8* BE0 = (const f16x8*)(wh + HOFF_E0);
  const f16x8* BE1 = (const f16x8*)(wh + HOFF_E1);
  const f16x8* BD0 = (const f16x8*)(wh + HOFF_D0);
  const f16x8* BD1 = (const f16x8*)(wh + HOFF_D1);
  const f16x8* BH  = (const f16x8*)(wh + HOFF_H);

  extern __shared__ __align__(16) f16 smem[];
  float* o1buf = (float*)(smem + L_HALVES);

  const int tid  = threadIdx.x;
  const int wv   = tid >> 6;
  const int lane = tid & 63;
  const int b0   = blockIdx.x * BM;
  const int lidx = lane & 15;

  for (int i = tid; i < L_HALVES; i += 512) smem[i] = (f16)0.f;   // zero h+x bufs
  float c0r[2][4] = {{0,0,0,0},{0,0,0,0}};
  float c1r[2][4] = {{0,0,0,0},{0,0,0,0}};
  f32x4 acc[2][4];

  const int lr = tid/6, ld = tid - (tid/6)*6;   // hist loader (tid<192)

  __syncthreads();   // zeros visible before x(0) seed
  if (tid < 192){    // x(0) -> x buf parity 1 (t=0 reads c^1 = 1)
    float v = hist[(b0+lr)*768 + ld];
    f16 hv = (f16)v;
    smem[L_XH + XBUF + lr*XS + ld] = hv;
    smem[L_XL + XBUF + lr*XS + ld] = (f16)(v - (float)hv);
  }
  __syncthreads();

  // ---------------- encoder: 128 steps, 2 barriers/step ----------------
  for (int t=0; t<128; ++t){
    const int c  = t & 1;            // write parity
    const int hw = c*HBUF, hr = (c^1)*HBUF;
    const int xw = c*XBUF, xr = (c^1)*XBUF;

    // P1: gemm0(t) + x(t+1) load + upd0 -> h0[c]
    init_acc(acc, wf + FB_E0, wv, lane);
    gemm2<5,4,XS>(acc, BE0,
                  smem + L_H0H + hr, smem + L_H0L + hr,
                  smem + L_XH  + xr, smem + L_XL  + xr, wv, lane);
    if (t < 127 && tid < 192){
      float v = hist[(b0+lr)*768 + (t+1)*6 + ld];
      f16 hv = (f16)v;
      smem[L_XH + xw + lr*XS + ld] = hv;
      smem[L_XL + xw + lr*XS + ld] = (f16)(v - (float)hv);
    }
    lstm_update_m(acc, c0r, smem + L_H0H + hw, smem + L_H0L + hw, wv, lane);
    __syncthreads();

    // P2: gemm1(t) reads h0[c], h1[c^1]; upd1 -> h1[c]
    init_acc(acc, wf + FB_E1, wv, lane);
    gemm2<8,4,HS>(acc, BE1,
                  smem + L_H0H + hw, smem + L_H0L + hw,
                  smem + L_H1H + hr, smem + L_H1L + hr, wv, lane);
    lstm_update_m(acc, c1r, smem + L_H1H + hw, smem + L_H1L + hw, wv, lane);
    __syncthreads();
  }

  // decoder seed: x = hist[:, -1, :2] -> x buf parity 1
  if (tid < 64){
    int r = tid>>1, j = tid&1;
    float v = hist[(b0+r)*768 + 762 + j];
    f16 hv = (f16)v;
    smem[L_XH + XBUF + r*XS + j] = hv;
    smem[L_XL + XBUF + r*XS + j] = (f16)(v - (float)hv);
  }
  __syncthreads();

  // ---------------- decoder: 125 steps, 5 barriers/step ----------------
  for (int t=0; t<125; ++t){
    const int c  = t & 1;
    const int hw = c*HBUF, hr = (c^1)*HBUF;
    const int xw = c*XBUF, xr = (c^1)*XBUF;

    // P1: gemm0 + upd0 -> h0[c]
    init_acc(acc, wf + FB_D0, wv, lane);
    gemm2<5,4,XS>(acc, BD0,
                  smem + L_H0H + hr, smem + L_H0L + hr,
                  smem + L_XH  + xr, smem + L_XL  + xr, wv, lane);
    lstm_update_m(acc, c0r, smem + L_H0H + hw, smem + L_H0L + hw, wv, lane);
    __syncthreads();

    // P2: gemm1 + upd1 -> h1[c]
    init_acc(acc, wf + FB_D1, wv, lane);
    gemm2<8,4,HS>(acc, BD1,
                  smem + L_H0H + hw, smem + L_H0L + hw,
                  smem + L_H1H + hr, smem + L_H1L + hr, wv, lane);
    lstm_update_m(acc, c1r, smem + L_H1H + hw, smem + L_H1L + hw, wv, lane);
    __syncthreads();

    // P3: head1: relu(h1(t) @ W1^T + b1) -> o1
    {
      const f16* h1wH = smem + L_H1H + hw;
      const f16* h1wL = smem + L_H1L + hw;
      float bH1 = wf[FB_H1 + wv*16 + lidx];
      f32x4 ha0 = {bH1,bH1,bH1,bH1};
      f32x4 ha1 = ha0;
#pragma unroll
      for (int kt=0;kt<4;++kt){
        f16x8 Wc = BH[(kt*8 + wv)*64 + lane];
        int kc = kt*32;
        f16x8 a0h = load_afrag<HS>(h1wH, 0, kc, lane);
        f16x8 a0l = load_afrag<HS>(h1wL, 0, kc, lane);
        f16x8 a1h = load_afrag<HS>(h1wH, 1, kc, lane);
        f16x8 a1l = load_afrag<HS>(h1wL, 1, kc, lane);
        ha0 = MFMA16(a0h, Wc, ha0);
        ha0 = MFMA16(a0l, Wc, ha0);
        ha1 = MFMA16(a1h, Wc, ha1);
        ha1 = MFMA16(a1l, Wc, ha1);
      }
#pragma unroll
      for (int r=0;r<4;++r){
        float v0 = ha0[r]; v0 = v0 > 0.f ? v0 : 0.f;
        float v1 = ha1[r]; v1 = v1 > 0.f ? v1 : 0.f;
        int rr = ((lane>>4)<<2) + r;
        o1buf[rr*O1S      + wv*16 + lidx] = v0;
        o1buf[(16+rr)*O1S + wv*16 + lidx] = v1;
      }
    }
    __syncthreads();

    // P4: head2 (parallel: 512 thr = 32 rows x 2 outs x 8 slices) + feedback
    {
      const int r = tid >> 4;          // 0..31
      const int j = (tid >> 3) & 1;
      const int s = tid & 7;
      const float* op = o1buf + r*O1S + s*16;
      const float* w2 = wf + FB_W2 + s*32 + j;
      float p0=0.f,p1=0.f,p2=0.f,p3=0.f;
#pragma unroll
      for (int i=0;i<16;i+=4){
        p0 = fmaf(op[i],   w2[2*i],   p0);
        p1 = fmaf(op[i+1], w2[2*i+2], p1);
        p2 = fmaf(op[i+2], w2[2*i+4], p2);
        p3 = fmaf(op[i+3], w2[2*i+6], p3);
      }
      float p = (p0+p1)+(p2+p3);
      p += __shfl_xor(p, 1);
      p += __shfl_xor(p, 2);
      p += __shfl_xor(p, 4);
      if (s == 0){
        float pred = wf[FB_B2 + j] + p;
        out[(b0+r)*250 + t*2 + j] = pred;
        f16 ph = (f16)pred;
        smem[L_XH + xw + r*XS + j] = ph;
        smem[L_XL + xw + r*XS + j] = (f16)(pred - (float)ph);
      }
    }
    __syncthreads();
  }
}

// ---------------------------------------------------------------------------
// setup: identical packing to rounds 5-15
// ---------------------------------------------------------------------------
__global__ void setup_kernel(
    const float* __restrict__ eWih0, const float* __restrict__ eWhh0,
    const float* __restrict__ ebih0, const float* __restrict__ ebhh0,
    const float* __restrict__ eWih1, const float* __restrict__ eWhh1,
    const float* __restrict__ ebih1, const float* __restrict__ ebhh1,
    const float* __restrict__ dWih0, const float* __restrict__ dWhh0,
    const float* __restrict__ dbih0, const float* __restrict__ dbhh0,
    const float* __restrict__ dWih1, const float* __restrict__ dWhh1,
    const float* __restrict__ dbih1, const float* __restrict__ dbhh1,
    const float* __restrict__ W1, const float* __restrict__ b1,
    const float* __restrict__ W2, const float* __restrict__ b2,
    float* __restrict__ ws)
{
  int i = blockIdx.x*256 + threadIdx.x;
  if (i < H_TOTAL){
    f16* whp = (f16*)ws;
    const float *Wa, *Wb; int ka, kb, off; bool head = false;
    if      (i < HOFF_E1){ off=HOFF_E0; Wa=eWhh0; ka=128; Wb=eWih0; kb=6; }
    else if (i < HOFF_D0){ off=HOFF_E1; Wa=eWih1; ka=128; Wb=eWhh1; kb=128; }
    else if (i < HOFF_D1){ off=HOFF_D0; Wa=dWhh0; ka=128; Wb=dWih0; kb=2; }
    else if (i < HOFF_H) { off=HOFF_D1; Wa=dWih1; ka=128; Wb=dWhh1; kb=128; }
    else                 { off=HOFF_H;  Wa=W1; ka=128; Wb=W1; kb=0; head=true; }
    int local = i - off;
    int j     = local & 7;
    int lane  = (local>>3) & 63;
    int nk    = local >> 9;
    int NTl   = head ? 8 : 32;
    int n     = nk % NTl;
    int kt    = nk / NTl;
    int col   = n*16 + (lane&15);
    int koff  = ((j>>2)<<4) + ((lane>>4)<<2) + (j&3);
    int kin   = kt*32 + koff;
    float val;
    if (head){
      val = (kin < 128) ? W1[col*128 + kin] : 0.f;
    } else {
      int orow = (col&3)*128 + (col>>2);
      val = (kin < ka) ? Wa[orow*ka + kin]
          : ((kin < ka+kb) ? Wb[orow*kb + (kin-ka)] : 0.f);
    }
    whp[i] = (f16)val;
  } else if (i < H_TOTAL + F_TOTAL){
    int f = i - H_TOTAL;
    float* wfp = ws + FOFF;
    if (f < 2048){
      int layer = f >> 9, c = f & 511;
      int orow = (c&3)*128 + (c>>2);
      const float *bi, *bh;
      if      (layer==0){ bi=ebih0; bh=ebhh0; }
      else if (layer==1){ bi=ebih1; bh=ebhh1; }
      else if (layer==2){ bi=dbih0; bh=dbhh0; }
      else              { bi=dbih1; bh=dbhh1; }
      wfp[f] = bi[orow] + bh[orow];
    } else if (f < 2176){
      wfp[f] = b1[f-2048];
    } else if (f < 2432){
      int k = (f-2176)>>1, j = (f-2176)&1;
      wfp[f] = W2[j*128 + k];
    } else {
      wfp[f] = b2[f-2432];
    }
  }
}

extern "C" void kernel_launch(void* const* d_in, const int* in_sizes, int n_in,
                              void* d_out, int out_size, void* d_ws, size_t ws_size,
                              hipStream_t stream)
{
  const float* hist = (const float*)d_in[0];
  float* ws = (float*)d_ws;

  (void)hipFuncSetAttribute(reinterpret_cast<const void*>(lstm_main),
                            hipFuncAttributeMaxDynamicSharedMemorySize, LDS_BYTES);

  int total = H_TOTAL + F_TOTAL;
  setup_kernel<<<(total + 255)/256, 256, 0, stream>>>(
      (const float*)d_in[1],  (const float*)d_in[2],
      (const float*)d_in[3],  (const float*)d_in[4],
      (const float*)d_in[5],  (const float*)d_in[6],
      (const float*)d_in[7],  (const float*)d_in[8],
      (const float*)d_in[9],  (const float*)d_in[10],
      (const float*)d_in[11], (const float*)d_in[12],
      (const float*)d_in[13], (const float*)d_in[14],
      (const float*)d_in[15], (const float*)d_in[16],
      (const float*)d_in[17], (const float*)d_in[18],
      (const float*)d_in[19], (const float*)d_in[20],
      ws);

  lstm_main<<<NBLK, 512, LDS_BYTES, stream>>>(hist, ws, (float*)d_out);
}

// Round 18
// 3428.472 us; speedup vs baseline: 1.2912x; 1.2912x over previous
//
#include <hip/hip_runtime.h>

// ---------------------------------------------------------------------------
// LSTM autoregressive, MI355X. Round 18: r13 (pacing restored, serial head2)
// + fp16-only h-planes (1-product for h, hi+lo kept only for x feedback).
//  - BM=32, 256 blocks x 512 thr, launch_bounds(512,2) [proven zero-spill]
//  - per-step MFMA 208 -> 112 instrs; h LDS reads/stores halved
//  - LDS 62 KB -> static __shared__
//  - lockstep pacing per step (r13-exact: groups of 32 via bid&7)
// ---------------------------------------------------------------------------

typedef _Float16 f16;
typedef _Float16 f16x4 __attribute__((ext_vector_type(4)));
typedef _Float16 f16x8 __attribute__((ext_vector_type(8)));
typedef float    f32x4 __attribute__((ext_vector_type(4)));

#define MFMA16(a,b,c) __builtin_amdgcn_mfma_f32_16x16x32_f16((a),(b),(c),0,0,0)

#define BM 32
#define NBLK 256
#define PACE_TGT 32   // blocks per pace group (NBLK/8)

// ws layout: fp16 B-hi fragments (halves), then fp32 region (floats)
#define HOFF_E0 0
#define HOFF_E1 81920
#define HOFF_D0 212992
#define HOFF_D1 294912
#define HOFF_H  425984
#define H_TOTAL 442368
#define FOFF    221184
#define FB_E0 0
#define FB_E1 512
#define FB_D0 1024
#define FB_D1 1536
#define FB_H1 2048
#define FB_W2 2176
#define FB_B2 2432
#define F_TOTAL 2434
#define BAR_F   2560     // 253 steps x 8 groups u32
#define BAR_BYTES 8192

#define HS 140    // h row stride (halves): 70 dw, 2-way free
#define XS 36     // x row stride (halves)
#define O1S 133   // o1 row stride (floats)

// LDS base offsets in halves; parity buffer at base + c*{HBUF,XBUF}
#define HBUF 4480         // 32*HS
#define XBUF 1152         // 32*XS
#define L_H0 0            // +c*HBUF  (hi only)
#define L_H1 8960         // +c*HBUF  (hi only)
#define L_XH 17920        // +c*XBUF
#define L_XL 20224        // +c*XBUF
#define L_HALVES 22528    // 45056 B; + o1buf 17024 B = 62080 B total (static)

__device__ __forceinline__ float fsig(float x){ return 1.0f/(1.0f+__expf(-x)); }
__device__ __forceinline__ float ftanh(float x){
  float a = fabsf(x);
  float e = __expf(-2.0f*a);
  float t = (1.0f-e)/(1.0f+e);
  return x < 0.0f ? -t : t;
}

// pacing barrier (r13-exact): pure performance device for lockstep weight
// streaming; 256 blocks = 1/CU co-resident, so the spin is safe.
__device__ __forceinline__ void grid_pace(unsigned* __restrict__ bar, int idx, int g, int tid){
  __syncthreads();
  if (tid == 0){
    unsigned* p = &bar[idx*8 + g];
    __hip_atomic_fetch_add(p, 1u, __ATOMIC_RELAXED, __HIP_MEMORY_SCOPE_AGENT);
    while (__hip_atomic_load(p, __ATOMIC_RELAXED, __HIP_MEMORY_SCOPE_AGENT) < (unsigned)PACE_TGT)
      __builtin_amdgcn_s_sleep(1);
  }
  __syncthreads();
}

// A fragment: row = m*16 + (lane&15); k = kc + (lane>>4)*4 + j (+16 for j>=4)
template<int STRIDE>
__device__ __forceinline__ f16x8 load_afrag(const f16* buf, int m, int kc, int lane){
  const f16* p = buf + (m*16 + (lane&15))*STRIDE + kc + ((lane>>4)<<2);
  f16x4 lo = *(const f16x4*)p;
  f16x4 hi = *(const f16x4*)(p+16);
  return __builtin_shufflevector(lo, hi, 0,1,2,3,4,5,6,7);
}

__device__ __forceinline__ void init_acc(f32x4 acc[2][4],
                                         const float* __restrict__ bias, int wv, int lane){
#pragma unroll
  for (int i=0;i<4;++i){
    float bv = bias[wv*64 + i*16 + (lane&15)];
    f32x4 b4 = {bv,bv,bv,bv};
    acc[0][i]=b4; acc[1][i]=b4;
  }
}

// gates[32 rows][wave's 64 cols] += [A(SPLIT kt, HS, hi-only) | C(rest, SB,
// hi + optional lo product)] * B_hi
template<int KT, int SPLIT, int SB, bool CLO>
__device__ __forceinline__ void gemm2(f32x4 acc[2][4],
    const f16x8* __restrict__ Bp,
    const f16* __restrict__ Ah,
    const f16* __restrict__ Ch, const f16* __restrict__ Cl,
    int wv, int lane)
{
  const int nb = wv*4;
  f16x8 Bc[4], Bn[4];
#pragma unroll
  for (int i=0;i<4;++i) Bc[i] = Bp[(nb + i)*64 + lane];
#pragma unroll
  for (int kt=0; kt<KT; ++kt){
    if (kt+1 < KT){
#pragma unroll
      for (int i=0;i<4;++i) Bn[i] = Bp[((kt+1)*32 + nb + i)*64 + lane];
    }
    if (kt < SPLIT){
      int kc = kt*32;
      f16x8 a0h = load_afrag<HS>(Ah, 0, kc, lane);
      f16x8 a1h = load_afrag<HS>(Ah, 1, kc, lane);
#pragma unroll
      for (int i=0;i<4;++i){
        acc[0][i] = MFMA16(a0h, Bc[i], acc[0][i]);
        acc[1][i] = MFMA16(a1h, Bc[i], acc[1][i]);
      }
    } else {
      int kc = (kt-SPLIT)*32;
      f16x8 c0h = load_afrag<SB>(Ch, 0, kc, lane);
      f16x8 c1h = load_afrag<SB>(Ch, 1, kc, lane);
#pragma unroll
      for (int i=0;i<4;++i){
        acc[0][i] = MFMA16(c0h, Bc[i], acc[0][i]);
        acc[1][i] = MFMA16(c1h, Bc[i], acc[1][i]);
      }
      if (CLO){
        f16x8 c0l = load_afrag<SB>(Cl, 0, kc, lane);
        f16x8 c1l = load_afrag<SB>(Cl, 1, kc, lane);
#pragma unroll
        for (int i=0;i<4;++i){
          acc[0][i] = MFMA16(c0l, Bc[i], acc[0][i]);
          acc[1][i] = MFMA16(c1l, Bc[i], acc[1][i]);
        }
      }
    }
#pragma unroll
    for (int i=0;i<4;++i) Bc[i] = Bn[i];
  }
}

// 4x4 transpose within a lane-quad
__device__ __forceinline__ void quad_transpose(float&a0,float&a1,float&a2,float&a3,int q){
  bool odd = (q & 1) != 0;
  float s0 = odd ? a0 : a1, s1 = odd ? a2 : a3;
  float r0 = __shfl_xor(s0,1), r1 = __shfl_xor(s1,1);
  float b0 = odd ? r0 : a0, b1 = odd ? a1 : r0;
  float b2 = odd ? r1 : a2, b3 = odd ? a3 : r1;
  bool hi = (q & 2) != 0;
  float u0 = hi ? b0 : b2, u1 = hi ? b1 : b3;
  float v0 = __shfl_xor(u0,2), v1 = __shfl_xor(u1,2);
  a0 = hi ? v0 : b0; a1 = hi ? v1 : b1;
  a2 = hi ? b2 : v0; a3 = hi ? b3 : v1;
}

__device__ __forceinline__ void lstm_update_m(f32x4 acc[2][4], float cr[2][4],
    f16* __restrict__ Dh, int wv, int lane)
{
  const int q = lane & 3;
  const int rsub = ((lane>>4)<<2) + q;
  const int usub = wv*16 + ((lane&15)>>2);
#pragma unroll
  for (int mt=0;mt<2;++mt)
#pragma unroll
  for (int nt=0;nt<4;++nt){
    float a0=acc[mt][nt][0], a1=acc[mt][nt][1], a2=acc[mt][nt][2], a3=acc[mt][nt][3];
    quad_transpose(a0,a1,a2,a3,q);
    float iv=fsig(a0), fv=fsig(a1), gv=ftanh(a2), ov=fsig(a3);
    float cn = fv*cr[mt][nt] + iv*gv;
    cr[mt][nt] = cn;
    float h = ov*ftanh(cn);
    int off = (mt*16 + rsub)*HS + usub + nt*4;
    Dh[off] = (f16)h;
  }
}

__global__ void __launch_bounds__(512, 2)
lstm_main(const float* __restrict__ hist, float* __restrict__ ws,
          float* __restrict__ out)
{
  const f16* wh = (const f16*)ws;
  const float* wf = ws + FOFF;
  unsigned* bar = (unsigned*)(ws + FOFF + BAR_F);
  const f16x8* BE0 = (const f16x8*)(wh + HOFF_E0);
  const f16x8* BE1 = (const f16x8*)(wh + HOFF_E1);
  const f16x8* BD0 = (const f16x8*)(wh + HOFF_D0);
  const f16x8* BD1 = (const f16x8*)(wh + HOFF_D1);
  const f16x8* BH  = (const f16x8*)(wh + HOFF_H);

  __shared__ __align__(16) f16 smem[L_HALVES];
  __shared__ __align__(16) float o1buf[32*O1S];

  const int tid  = threadIdx.x;
  const int wv   = tid >> 6;
  const int lane = tid & 63;
  const int b0   = blockIdx.x * BM;
  const int g    = blockIdx.x & 7;
  const int lidx = lane & 15;

  for (int i = tid; i < L_HALVES; i += 512) smem[i] = (f16)0.f;   // zero h+x bufs
  float c0r[2][4] = {{0,0,0,0},{0,0,0,0}};
  float c1r[2][4] = {{0,0,0,0},{0,0,0,0}};
  f32x4 acc[2][4];

  const int lr = tid/6, ld = tid - (tid/6)*6;   // hist loader (tid<192)

  __syncthreads();   // zeros visible before x(0) seed
  if (tid < 192){    // x(0) -> x buf parity 1 (t=0 reads c^1 = 1)
    float v = hist[(b0+lr)*768 + ld];
    f16 hv = (f16)v;
    smem[L_XH + XBUF + lr*XS + ld] = hv;
    smem[L_XL + XBUF + lr*XS + ld] = (f16)(v - (float)hv);
  }
  __syncthreads();

  // ---------------- encoder: 128 steps, 2 barriers + pace ----------------
  for (int t=0; t<128; ++t){
    const int c  = t & 1;            // write parity
    const int hw = c*HBUF, hr = (c^1)*HBUF;
    const int xw = c*XBUF, xr = (c^1)*XBUF;

    // P1: gemm0(t) [h0 hi, x hi+lo] + x(t+1) load + upd0 -> h0[c]
    init_acc(acc, wf + FB_E0, wv, lane);
    gemm2<5,4,XS,true>(acc, BE0,
                       smem + L_H0 + hr,
                       smem + L_XH + xr, smem + L_XL + xr, wv, lane);
    if (t < 127 && tid < 192){
      float v = hist[(b0+lr)*768 + (t+1)*6 + ld];
      f16 hv = (f16)v;
      smem[L_XH + xw + lr*XS + ld] = hv;
      smem[L_XL + xw + lr*XS + ld] = (f16)(v - (float)hv);
    }
    lstm_update_m(acc, c0r, smem + L_H0 + hw, wv, lane);
    __syncthreads();

    // P2: gemm1(t) reads h0[c], h1[c^1] (hi only); upd1 -> h1[c]
    init_acc(acc, wf + FB_E1, wv, lane);
    gemm2<8,4,HS,false>(acc, BE1,
                        smem + L_H0 + hw,
                        smem + L_H1 + hr, smem + L_H1 + hr, wv, lane);
    lstm_update_m(acc, c1r, smem + L_H1 + hw, wv, lane);
    grid_pace(bar, t, g, tid);       // closes the step
  }

  // decoder seed: x = hist[:, -1, :2] -> x buf parity 1
  if (tid < 64){
    int r = tid>>1, j = tid&1;
    float v = hist[(b0+r)*768 + 762 + j];
    f16 hv = (f16)v;
    smem[L_XH + XBUF + r*XS + j] = hv;
    smem[L_XL + XBUF + r*XS + j] = (f16)(v - (float)hv);
  }
  __syncthreads();

  // ---------------- decoder: 125 steps ----------------
  for (int t=0; t<125; ++t){
    const int c  = t & 1;
    const int hw = c*HBUF, hr = (c^1)*HBUF;
    const int xw = c*XBUF, xr = (c^1)*XBUF;

    // P1: gemm0 + upd0 -> h0[c]
    init_acc(acc, wf + FB_D0, wv, lane);
    gemm2<5,4,XS,true>(acc, BD0,
                       smem + L_H0 + hr,
                       smem + L_XH + xr, smem + L_XL + xr, wv, lane);
    lstm_update_m(acc, c0r, smem + L_H0 + hw, wv, lane);
    __syncthreads();

    // P2: gemm1 + upd1 -> h1[c]
    init_acc(acc, wf + FB_D1, wv, lane);
    gemm2<8,4,HS,false>(acc, BD1,
                        smem + L_H0 + hw,
                        smem + L_H1 + hr, smem + L_H1 + hr, wv, lane);
    lstm_update_m(acc, c1r, smem + L_H1 + hw, wv, lane);
    __syncthreads();

    // P3: head1: relu(h1(t) @ W1^T + b1) -> o1 (hi only)
    {
      const f16* h1wH = smem + L_H1 + hw;
      float bH1 = wf[FB_H1 + wv*16 + lidx];
      f32x4 ha0 = {bH1,bH1,bH1,bH1};
      f32x4 ha1 = ha0;
#pragma unroll
      for (int kt=0;kt<4;++kt){
        f16x8 Wc = BH[(kt*8 + wv)*64 + lane];
        int kc = kt*32;
        f16x8 a0h = load_afrag<HS>(h1wH, 0, kc, lane);
        f16x8 a1h = load_afrag<HS>(h1wH, 1, kc, lane);
        ha0 = MFMA16(a0h, Wc, ha0);
        ha1 = MFMA16(a1h, Wc, ha1);
      }
#pragma unroll
      for (int r=0;r<4;++r){
        float v0 = ha0[r]; v0 = v0 > 0.f ? v0 : 0.f;
        float v1 = ha1[r]; v1 = v1 > 0.f ? v1 : 0.f;
        int rr = ((lane>>4)<<2) + r;
        o1buf[rr*O1S      + wv*16 + lidx] = v0;
        o1buf[(16+rr)*O1S + wv*16 + lidx] = v1;
      }
    }
    __syncthreads();

    // P4: head2 (serial r13 form) -> out + x(t+1) into x buf [c]
    if (tid < 64){
      int r = tid>>1, j = tid&1;
      const float* op = o1buf + r*O1S;
      const float* w2 = wf + FB_W2 + j;
      float s0=0.f,s1=0.f,s2=0.f,s3=0.f;
#pragma unroll
      for (int k=0;k<128;k+=4){
        s0 = fmaf(op[k],   w2[2*k],   s0);
        s1 = fmaf(op[k+1], w2[2*k+2], s1);
        s2 = fmaf(op[k+2], w2[2*k+4], s2);
        s3 = fmaf(op[k+3], w2[2*k+6], s3);
      }
      float pred = wf[FB_B2 + j] + ((s0+s1)+(s2+s3));
      out[(b0+r)*250 + t*2 + j] = pred;
      f16 ph = (f16)pred;
      smem[L_XH + xw + r*XS + j] = ph;
      smem[L_XL + xw + r*XS + j] = (f16)(pred - (float)ph);
    }
    grid_pace(bar, 128 + t, g, tid);
  }
}

// ---------------------------------------------------------------------------
// setup: identical packing to rounds 5-17
// ---------------------------------------------------------------------------
__global__ void setup_kernel(
    const float* __restrict__ eWih0, const float* __restrict__ eWhh0,
    const float* __restrict__ ebih0, const float* __restrict__ ebhh0,
    const float* __restrict__ eWih1, const float* __restrict__ eWhh1,
    const float* __restrict__ ebih1, const float* __restrict__ ebhh1,
    const float* __restrict__ dWih0, const float* __restrict__ dWhh0,
    const float* __restrict__ dbih0, const float* __restrict__ dbhh0,
    const float* __restrict__ dWih1, const float* __restrict__ dWhh1,
    const float* __restrict__ dbih1, const float* __restrict__ dbhh1,
    const float* __restrict__ W1, const float* __restrict__ b1,
    const float* __restrict__ W2, const float* __restrict__ b2,
    float* __restrict__ ws)
{
  int i = blockIdx.x*256 + threadIdx.x;
  if (i < H_TOTAL){
    f16* whp = (f16*)ws;
    const float *Wa, *Wb; int ka, kb, off; bool head = false;
    if      (i < HOFF_E1){ off=HOFF_E0; Wa=eWhh0; ka=128; Wb=eWih0; kb=6; }
    else if (i < HOFF_D0){ off=HOFF_E1; Wa=eWih1; ka=128; Wb=eWhh1; kb=128; }
    else if (i < HOFF_D1){ off=HOFF_D0; Wa=dWhh0; ka=128; Wb=dWih0; kb=2; }
    else if (i < HOFF_H) { off=HOFF_D1; Wa=dWih1; ka=128; Wb=dWhh1; kb=128; }
    else                 { off=HOFF_H;  Wa=W1; ka=128; Wb=W1; kb=0; head=true; }
    int local = i - off;
    int j     = local & 7;
    int lane  = (local>>3) & 63;
    int nk    = local >> 9;
    int NTl   = head ? 8 : 32;
    int n     = nk % NTl;
    int kt    = nk / NTl;
    int col   = n*16 + (lane&15);
    int koff  = ((j>>2)<<4) + ((lane>>4)<<2) + (j&3);
    int kin   = kt*32 + koff;
    float val;
    if (head){
      val = (kin < 128) ? W1[col*128 + kin] : 0.f;
    } else {
      int orow = (col&3)*128 + (col>>2);
      val = (kin < ka) ? Wa[orow*ka + kin]
          : ((kin < ka+kb) ? Wb[orow*kb + (kin-ka)] : 0.f);
    }
    whp[i] = (f16)val;
  } else if (i < H_TOTAL + F_TOTAL){
    int f = i - H_TOTAL;
    float* wfp = ws + FOFF;
    if (f < 2048){
      int layer = f >> 9, c = f & 511;
      int orow = (c&3)*128 + (c>>2);
      const float *bi, *bh;
      if      (layer==0){ bi=ebih0; bh=ebhh0; }
      else if (layer==1){ bi=ebih1; bh=ebhh1; }
      else if (layer==2){ bi=dbih0; bh=dbhh0; }
      else              { bi=dbih1; bh=dbhh1; }
      wfp[f] = bi[orow] + bh[orow];
    } else if (f < 2176){
      wfp[f] = b1[f-2048];
    } else if (f < 2432){
      int k = (f-2176)>>1, j = (f-2176)&1;
      wfp[f] = W2[j*128 + k];
    } else {
      wfp[f] = b2[f-2432];
    }
  }
}

extern "C" void kernel_launch(void* const* d_in, const int* in_sizes, int n_in,
                              void* d_out, int out_size, void* d_ws, size_t ws_size,
                              hipStream_t stream)
{
  const float* hist = (const float*)d_in[0];
  float* ws = (float*)d_ws;

  // zero the pacing-barrier counters (capture-safe async memset)
  (void)hipMemsetAsync((char*)d_ws + (size_t)(FOFF + BAR_F)*4, 0, BAR_BYTES, stream);

  int total = H_TOTAL + F_TOTAL;
  setup_kernel<<<(total + 255)/256, 256, 0, stream>>>(
      (const float*)d_in[1],  (const float*)d_in[2],
      (const float*)d_in[3],  (const float*)d_in[4],
      (const float*)d_in[5],  (const float*)d_in[6],
      (const float*)d_in[7],  (const float*)d_in[8],
      (const float*)d_in[9],  (const float*)d_in[10],
      (const float*)d_in[11], (const float*)d_in[12],
      (const float*)d_in[13], (const float*)d_in[14],
      (const float*)d_in[15], (const float*)d_in[16],
      (const float*)d_in[17], (const float*)d_in[18],
      (const float*)d_in[19], (const float*)d_in[20],
      ws);

  lstm_main<<<NBLK, 512, 0, stream>>>(hist, ws, (float*)d_out);
}

// Round 19
// 2915.723 us; speedup vs baseline: 1.5182x; 1.1759x over previous
//
#include <hip/hip_runtime.h>

// ---------------------------------------------------------------------------
// LSTM autoregressive, MI355X. Round 19: gate-major B packing -> transpose-
// free LSTM update (no shfl, no selects; ~250 VALU instrs/thread/step saved).
//  - col = gate*128 + unit (original layout; setup orow = col identity)
//  - wave wv owns ntiles {wv, 8+wv, 16+wv, 24+wv} = 4 gates x units[wv*16..+16)
//  - acc[mt][g][r] = gate g of (row, unit) -> update is pure per-thread math
//  - rest = r18: BM=32, 256 blk x 512 thr (512,2), 1-product h (hi fp16),
//    x hi+lo, double-buffered h/x, per-step lockstep pacing, serial head2
// ---------------------------------------------------------------------------

typedef _Float16 f16;
typedef _Float16 f16x4 __attribute__((ext_vector_type(4)));
typedef _Float16 f16x8 __attribute__((ext_vector_type(8)));
typedef float    f32x4 __attribute__((ext_vector_type(4)));

#define MFMA16(a,b,c) __builtin_amdgcn_mfma_f32_16x16x32_f16((a),(b),(c),0,0,0)

#define BM 32
#define NBLK 256
#define PACE_TGT 32   // blocks per pace group (NBLK/8)

// ws layout: fp16 B-hi fragments (halves), then fp32 region (floats)
#define HOFF_E0 0
#define HOFF_E1 81920
#define HOFF_D0 212992
#define HOFF_D1 294912
#define HOFF_H  425984
#define H_TOTAL 442368
#define FOFF    221184
#define FB_E0 0
#define FB_E1 512
#define FB_D0 1024
#define FB_D1 1536
#define FB_H1 2048
#define FB_W2 2176
#define FB_B2 2432
#define F_TOTAL 2434
#define BAR_F   2560     // 253 steps x 8 groups u32
#define BAR_BYTES 8192

#define HS 140    // h row stride (halves): 70 dw, 2-way free
#define XS 36     // x row stride (halves)
#define O1S 133   // o1 row stride (floats)

// LDS base offsets in halves; parity buffer at base + c*{HBUF,XBUF}
#define HBUF 4480         // 32*HS
#define XBUF 1152         // 32*XS
#define L_H0 0            // +c*HBUF  (hi only)
#define L_H1 8960         // +c*HBUF  (hi only)
#define L_XH 17920        // +c*XBUF
#define L_XL 20224        // +c*XBUF
#define L_HALVES 22528

__device__ __forceinline__ float fsig(float x){ return 1.0f/(1.0f+__expf(-x)); }
__device__ __forceinline__ float ftanh(float x){
  float a = fabsf(x);
  float e = __expf(-2.0f*a);
  float t = (1.0f-e)/(1.0f+e);
  return x < 0.0f ? -t : t;
}

// pacing barrier: pure performance device for lockstep weight streaming;
// 256 blocks = 1/CU co-resident, so the spin is safe.
__device__ __forceinline__ void grid_pace(unsigned* __restrict__ bar, int idx, int g, int tid){
  __syncthreads();
  if (tid == 0){
    unsigned* p = &bar[idx*8 + g];
    __hip_atomic_fetch_add(p, 1u, __ATOMIC_RELAXED, __HIP_MEMORY_SCOPE_AGENT);
    while (__hip_atomic_load(p, __ATOMIC_RELAXED, __HIP_MEMORY_SCOPE_AGENT) < (unsigned)PACE_TGT)
      __builtin_amdgcn_s_sleep(1);
  }
  __syncthreads();
}

// A fragment: row = m*16 + (lane&15); k = kc + (lane>>4)*4 + j (+16 for j>=4)
template<int STRIDE>
__device__ __forceinline__ f16x8 load_afrag(const f16* buf, int m, int kc, int lane){
  const f16* p = buf + (m*16 + (lane&15))*STRIDE + kc + ((lane>>4)<<2);
  f16x4 lo = *(const f16x4*)p;
  f16x4 hi = *(const f16x4*)(p+16);
  return __builtin_shufflevector(lo, hi, 0,1,2,3,4,5,6,7);
}

// acc[mt][g] accumulates gate g (ntile g*8+wv) for rows mt*16..mt*16+15
__device__ __forceinline__ void init_acc(f32x4 acc[2][4],
                                         const float* __restrict__ bias, int wv, int lane){
#pragma unroll
  for (int i=0;i<4;++i){
    float bv = bias[i*128 + wv*16 + (lane&15)];
    f32x4 b4 = {bv,bv,bv,bv};
    acc[0][i]=b4; acc[1][i]=b4;
  }
}

// gates[32 rows][4 gates x 16 units] += [A(SPLIT kt, HS, hi) | C(rest, SB,
// hi + optional lo product)] * B_hi     (ntile for gate i = i*8 + wv)
template<int KT, int SPLIT, int SB, bool CLO>
__device__ __forceinline__ void gemm2(f32x4 acc[2][4],
    const f16x8* __restrict__ Bp,
    const f16* __restrict__ Ah,
    const f16* __restrict__ Ch, const f16* __restrict__ Cl,
    int wv, int lane)
{
  f16x8 Bc[4], Bn[4];
#pragma unroll
  for (int i=0;i<4;++i) Bc[i] = Bp[(i*8 + wv)*64 + lane];
#pragma unroll
  for (int kt=0; kt<KT; ++kt){
    if (kt+1 < KT){
#pragma unroll
      for (int i=0;i<4;++i) Bn[i] = Bp[((kt+1)*32 + i*8 + wv)*64 + lane];
    }
    if (kt < SPLIT){
      int kc = kt*32;
      f16x8 a0h = load_afrag<HS>(Ah, 0, kc, lane);
      f16x8 a1h = load_afrag<HS>(Ah, 1, kc, lane);
#pragma unroll
      for (int i=0;i<4;++i){
        acc[0][i] = MFMA16(a0h, Bc[i], acc[0][i]);
        acc[1][i] = MFMA16(a1h, Bc[i], acc[1][i]);
      }
    } else {
      int kc = (kt-SPLIT)*32;
      f16x8 c0h = load_afrag<SB>(Ch, 0, kc, lane);
      f16x8 c1h = load_afrag<SB>(Ch, 1, kc, lane);
#pragma unroll
      for (int i=0;i<4;++i){
        acc[0][i] = MFMA16(c0h, Bc[i], acc[0][i]);
        acc[1][i] = MFMA16(c1h, Bc[i], acc[1][i]);
      }
      if (CLO){
        f16x8 c0l = load_afrag<SB>(Cl, 0, kc, lane);
        f16x8 c1l = load_afrag<SB>(Cl, 1, kc, lane);
#pragma unroll
        for (int i=0;i<4;++i){
          acc[0][i] = MFMA16(c0l, Bc[i], acc[0][i]);
          acc[1][i] = MFMA16(c1l, Bc[i], acc[1][i]);
        }
      }
    }
#pragma unroll
    for (int i=0;i<4;++i) Bc[i] = Bn[i];
  }
}

// transpose-free update: acc[mt][0..3][r] = (i,f,g,o) of (row mt*16+rg+r,
// unit wv*16+(lane&15)); C/D layout col=lane&15, row=(lane>>4)*4+r [m89]
__device__ __forceinline__ void lstm_update_m(f32x4 acc[2][4], float cr[2][4],
    f16* __restrict__ Dh, int wv, int lane)
{
  const int unit = wv*16 + (lane&15);
  const int rg   = (lane>>4)<<2;
#pragma unroll
  for (int mt=0;mt<2;++mt)
#pragma unroll
  for (int r=0;r<4;++r){
    float iv = fsig(acc[mt][0][r]);
    float fv = fsig(acc[mt][1][r]);
    float gv = ftanh(acc[mt][2][r]);
    float ov = fsig(acc[mt][3][r]);
    float cn = fv*cr[mt][r] + iv*gv;
    cr[mt][r] = cn;
    float h = ov*ftanh(cn);
    Dh[(mt*16 + rg + r)*HS + unit] = (f16)h;
  }
}

__global__ void __launch_bounds__(512, 2)
lstm_main(const float* __restrict__ hist, float* __restrict__ ws,
          float* __restrict__ out)
{
  const f16* wh = (const f16*)ws;
  const float* wf = ws + FOFF;
  unsigned* bar = (unsigned*)(ws + FOFF + BAR_F);
  const f16x8* BE0 = (const f16x8*)(wh + HOFF_E0);
  const f16x8* BE1 = (const f16x8*)(wh + HOFF_E1);
  const f16x8* BD0 = (const f16x8*)(wh + HOFF_D0);
  const f16x8* BD1 = (const f16x8*)(wh + HOFF_D1);
  const f16x8* BH  = (const f16x8*)(wh + HOFF_H);

  __shared__ __align__(16) f16 smem[L_HALVES];
  __shared__ __align__(16) float o1buf[32*O1S];

  const int tid  = threadIdx.x;
  const int wv   = tid >> 6;
  const int lane = tid & 63;
  const int b0   = blockIdx.x * BM;
  const int g    = blockIdx.x & 7;
  const int lidx = lane & 15;

  for (int i = tid; i < L_HALVES; i += 512) smem[i] = (f16)0.f;   // zero h+x bufs
  float c0r[2][4] = {{0,0,0,0},{0,0,0,0}};
  float c1r[2][4] = {{0,0,0,0},{0,0,0,0}};
  f32x4 acc[2][4];

  const int lr = tid/6, ld = tid - (tid/6)*6;   // hist loader (tid<192)

  __syncthreads();   // zeros visible before x(0) seed
  if (tid < 192){    // x(0) -> x buf parity 1 (t=0 reads c^1 = 1)
    float v = hist[(b0+lr)*768 + ld];
    f16 hv = (f16)v;
    smem[L_XH + XBUF + lr*XS + ld] = hv;
    smem[L_XL + XBUF + lr*XS + ld] = (f16)(v - (float)hv);
  }
  __syncthreads();

  // ---------------- encoder: 128 steps, 2 barriers + pace ----------------
  for (int t=0; t<128; ++t){
    const int c  = t & 1;            // write parity
    const int hw = c*HBUF, hr = (c^1)*HBUF;
    const int xw = c*XBUF, xr = (c^1)*XBUF;

    // P1: gemm0(t) [h0 hi, x hi+lo] + x(t+1) load + upd0 -> h0[c]
    init_acc(acc, wf + FB_E0, wv, lane);
    gemm2<5,4,XS,true>(acc, BE0,
                       smem + L_H0 + hr,
                       smem + L_XH + xr, smem + L_XL + xr, wv, lane);
    if (t < 127 && tid < 192){
      float v = hist[(b0+lr)*768 + (t+1)*6 + ld];
      f16 hv = (f16)v;
      smem[L_XH + xw + lr*XS + ld] = hv;
      smem[L_XL + xw + lr*XS + ld] = (f16)(v - (float)hv);
    }
    lstm_update_m(acc, c0r, smem + L_H0 + hw, wv, lane);
    __syncthreads();

    // P2: gemm1(t) reads h0[c], h1[c^1] (hi only); upd1 -> h1[c]
    init_acc(acc, wf + FB_E1, wv, lane);
    gemm2<8,4,HS,false>(acc, BE1,
                        smem + L_H0 + hw,
                        smem + L_H1 + hr, smem + L_H1 + hr, wv, lane);
    lstm_update_m(acc, c1r, smem + L_H1 + hw, wv, lane);
    grid_pace(bar, t, g, tid);       // closes the step
  }

  // decoder seed: x = hist[:, -1, :2] -> x buf parity 1
  if (tid < 64){
    int r = tid>>1, j = tid&1;
    float v = hist[(b0+r)*768 + 762 + j];
    f16 hv = (f16)v;
    smem[L_XH + XBUF + r*XS + j] = hv;
    smem[L_XL + XBUF + r*XS + j] = (f16)(v - (float)hv);
  }
  __syncthreads();

  // ---------------- decoder: 125 steps ----------------
  for (int t=0; t<125; ++t){
    const int c  = t & 1;
    const int hw = c*HBUF, hr = (c^1)*HBUF;
    const int xw = c*XBUF, xr = (c^1)*XBUF;

    // P1: gemm0 + upd0 -> h0[c]
    init_acc(acc, wf + FB_D0, wv, lane);
    gemm2<5,4,XS,true>(acc, BD0,
                       smem + L_H0 + hr,
                       smem + L_XH + xr, smem + L_XL + xr, wv, lane);
    lstm_update_m(acc, c0r, smem + L_H0 + hw, wv, lane);
    __syncthreads();

    // P2: gemm1 + upd1 -> h1[c]
    init_acc(acc, wf + FB_D1, wv, lane);
    gemm2<8,4,HS,false>(acc, BD1,
                        smem + L_H0 + hw,
                        smem + L_H1 + hr, smem + L_H1 + hr, wv, lane);
    lstm_update_m(acc, c1r, smem + L_H1 + hw, wv, lane);
    __syncthreads();

    // P3: head1: relu(h1(t) @ W1^T + b1) -> o1 (hi only)
    {
      const f16* h1wH = smem + L_H1 + hw;
      float bH1 = wf[FB_H1 + wv*16 + lidx];
      f32x4 ha0 = {bH1,bH1,bH1,bH1};
      f32x4 ha1 = ha0;
#pragma unroll
      for (int kt=0;kt<4;++kt){
        f16x8 Wc = BH[(kt*8 + wv)*64 + lane];
        int kc = kt*32;
        f16x8 a0h = load_afrag<HS>(h1wH, 0, kc, lane);
        f16x8 a1h = load_afrag<HS>(h1wH, 1, kc, lane);
        ha0 = MFMA16(a0h, Wc, ha0);
        ha1 = MFMA16(a1h, Wc, ha1);
      }
#pragma unroll
      for (int r=0;r<4;++r){
        float v0 = ha0[r]; v0 = v0 > 0.f ? v0 : 0.f;
        float v1 = ha1[r]; v1 = v1 > 0.f ? v1 : 0.f;
        int rr = ((lane>>4)<<2) + r;
        o1buf[rr*O1S      + wv*16 + lidx] = v0;
        o1buf[(16+rr)*O1S + wv*16 + lidx] = v1;
      }
    }
    __syncthreads();

    // P4: head2 (serial r13 form) -> out + x(t+1) into x buf [c]
    if (tid < 64){
      int r = tid>>1, j = tid&1;
      const float* op = o1buf + r*O1S;
      const float* w2 = wf + FB_W2 + j;
      float s0=0.f,s1=0.f,s2=0.f,s3=0.f;
#pragma unroll
      for (int k=0;k<128;k+=4){
        s0 = fmaf(op[k],   w2[2*k],   s0);
        s1 = fmaf(op[k+1], w2[2*k+2], s1);
        s2 = fmaf(op[k+2], w2[2*k+4], s2);
        s3 = fmaf(op[k+3], w2[2*k+6], s3);
      }
      float pred = wf[FB_B2 + j] + ((s0+s1)+(s2+s3));
      out[(b0+r)*250 + t*2 + j] = pred;
      f16 ph = (f16)pred;
      smem[L_XH + xw + r*XS + j] = ph;
      smem[L_XL + xw + r*XS + j] = (f16)(pred - (float)ph);
    }
    grid_pace(bar, 128 + t, g, tid);
  }
}

// ---------------------------------------------------------------------------
// setup: pack B-hi weights, gate-major columns (col = gate*128 + unit =
// ORIGINAL row index -> orow = col identity). k-fragment map unchanged.
// ---------------------------------------------------------------------------
__global__ void setup_kernel(
    const float* __restrict__ eWih0, const float* __restrict__ eWhh0,
    const float* __restrict__ ebih0, const float* __restrict__ ebhh0,
    const float* __restrict__ eWih1, const float* __restrict__ eWhh1,
    const float* __restrict__ ebih1, const float* __restrict__ ebhh1,
    const float* __restrict__ dWih0, const float* __restrict__ dWhh0,
    const float* __restrict__ dbih0, const float* __restrict__ dbhh0,
    const float* __restrict__ dWih1, const float* __restrict__ dWhh1,
    const float* __restrict__ dbih1, const float* __restrict__ dbhh1,
    const float* __restrict__ W1, const float* __restrict__ b1,
    const float* __restrict__ W2, const float* __restrict__ b2,
    float* __restrict__ ws)
{
  int i = blockIdx.x*256 + threadIdx.x;
  if (i < H_TOTAL){
    f16* whp = (f16*)ws;
    const float *Wa, *Wb; int ka, kb, off; bool head = false;
    if      (i < HOFF_E1){ off=HOFF_E0; Wa=eWhh0; ka=128; Wb=eWih0; kb=6; }
    else if (i < HOFF_D0){ off=HOFF_E1; Wa=eWih1; ka=128; Wb=eWhh1; kb=128; }
    else if (i < HOFF_D1){ off=HOFF_D0; Wa=dWhh0; ka=128; Wb=dWih0; kb=2; }
    else if (i < HOFF_H) { off=HOFF_D1; Wa=dWih1; ka=128; Wb=dWhh1; kb=128; }
    else                 { off=HOFF_H;  Wa=W1; ka=128; Wb=W1; kb=0; head=true; }
    int local = i - off;
    int j     = local & 7;
    int lane  = (local>>3) & 63;
    int nk    = local >> 9;
    int NTl   = head ? 8 : 32;
    int n     = nk % NTl;
    int kt    = nk / NTl;
    int col   = n*16 + (lane&15);
    int koff  = ((j>>2)<<4) + ((lane>>4)<<2) + (j&3);
    int kin   = kt*32 + koff;
    float val;
    if (head){
      val = (kin < 128) ? W1[col*128 + kin] : 0.f;
    } else {
      val = (kin < ka) ? Wa[col*ka + kin]
          : ((kin < ka+kb) ? Wb[col*kb + (kin-ka)] : 0.f);
    }
    whp[i] = (f16)val;
  } else if (i < H_TOTAL + F_TOTAL){
    int f = i - H_TOTAL;
    float* wfp = ws + FOFF;
    if (f < 2048){
      int layer = f >> 9, c = f & 511;
      const float *bi, *bh;
      if      (layer==0){ bi=ebih0; bh=ebhh0; }
      else if (layer==1){ bi=ebih1; bh=ebhh1; }
      else if (layer==2){ bi=dbih0; bh=dbhh0; }
      else              { bi=dbih1; bh=dbhh1; }
      wfp[f] = bi[c] + bh[c];
    } else if (f < 2176){
      wfp[f] = b1[f-2048];
    } else if (f < 2432){
      int k = (f-2176)>>1, j = (f-2176)&1;
      wfp[f] = W2[j*128 + k];
    } else {
      wfp[f] = b2[f-2432];
    }
  }
}

extern "C" void kernel_launch(void* const* d_in, const int* in_sizes, int n_in,
                              void* d_out, int out_size, void* d_ws, size_t ws_size,
                              hipStream_t stream)
{
  const float* hist = (const float*)d_in[0];
  float* ws = (float*)d_ws;

  // zero the pacing-barrier counters (capture-safe async memset)
  (void)hipMemsetAsync((char*)d_ws + (size_t)(FOFF + BAR_F)*4, 0, BAR_BYTES, stream);

  int total = H_TOTAL + F_TOTAL;
  setup_kernel<<<(total + 255)/256, 256, 0, stream>>>(
      (const float*)d_in[1],  (const float*)d_in[2],
      (const float*)d_in[3],  (const float*)d_in[4],
      (const float*)d_in[5],  (const float*)d_in[6],
      (const float*)d_in[7],  (const float*)d_in[8],
      (const float*)d_in[9],  (const float*)d_in[10],
      (const float*)d_in[11], (const float*)d_in[12],
      (const float*)d_in[13], (const float*)d_in[14],
      (const float*)d_in[15], (const float*)d_in[16],
      (const float*)d_in[17], (const float*)d_in[18],
      (const float*)d_in[19], (const float*)d_in[20],
      ws);

  lstm_main<<<NBLK, 512, 0, stream>>>(hist, ws, (float*)d_out);
}

// Round 20
// 2698.857 us; speedup vs baseline: 1.6402x; 1.0804x over previous
//
#include <hip/hip_runtime.h>

// ---------------------------------------------------------------------------
// LSTM autoregressive, MI355X. Round 20: sync-thinning on r19.
//  - encoder: step-end barrier REMOVED (dependency-proof: double-buffered
//    h/x make P2(t) and P1(t+1) conflict-free); 1 barrier/step + pace/2 steps
//  - decoder: pace every 2nd step (plain barrier on off steps)
//  - head2: conflict-free parallel form (512 thr, lane s reads o1[i*8+s],
//    <=2-way bank aliasing = free; shfl_xor reduce) replaces 64-thr serial
//  - pace counters per-group cache lines: bar[g*128 + idx]
//  - rest = r19: gate-major B, transpose-free update, 1-product h, BM=32,
//    256 blk x 512 thr (512,2)
// ---------------------------------------------------------------------------

typedef _Float16 f16;
typedef _Float16 f16x4 __attribute__((ext_vector_type(4)));
typedef _Float16 f16x8 __attribute__((ext_vector_type(8)));
typedef float    f32x4 __attribute__((ext_vector_type(4)));

#define MFMA16(a,b,c) __builtin_amdgcn_mfma_f32_16x16x32_f16((a),(b),(c),0,0,0)

#define BM 32
#define NBLK 256
#define PACE_TGT 32   // blocks per pace group (NBLK/8)

// ws layout: fp16 B-hi fragments (halves), then fp32 region (floats)
#define HOFF_E0 0
#define HOFF_E1 81920
#define HOFF_D0 212992
#define HOFF_D1 294912
#define HOFF_H  425984
#define H_TOTAL 442368
#define FOFF    221184
#define FB_E0 0
#define FB_E1 512
#define FB_D0 1024
#define FB_D1 1536
#define FB_H1 2048
#define FB_W2 2176
#define FB_B2 2432
#define F_TOTAL 2434
#define BAR_F   2560     // bar[g*128 + idx], 8 groups x 128 pace events
#define BAR_BYTES 4096

#define HS 140    // h row stride (halves): 70 dw, 2-way free
#define XS 36     // x row stride (halves)
#define O1S 133   // o1 row stride (floats)

// LDS base offsets in halves; parity buffer at base + c*{HBUF,XBUF}
#define HBUF 4480         // 32*HS
#define XBUF 1152         // 32*XS
#define L_H0 0            // +c*HBUF  (hi only)
#define L_H1 8960         // +c*HBUF  (hi only)
#define L_XH 17920        // +c*XBUF
#define L_XL 20224        // +c*XBUF
#define L_HALVES 22528

__device__ __forceinline__ float fsig(float x){ return 1.0f/(1.0f+__expf(-x)); }
__device__ __forceinline__ float ftanh(float x){
  float a = fabsf(x);
  float e = __expf(-2.0f*a);
  float t = (1.0f-e)/(1.0f+e);
  return x < 0.0f ? -t : t;
}

// pacing barrier: pure performance device for lockstep weight streaming;
// 256 blocks = 1/CU co-resident, so the spin is safe.
__device__ __forceinline__ void grid_pace(unsigned* __restrict__ bar, int idx, int g, int tid){
  __syncthreads();
  if (tid == 0){
    unsigned* p = &bar[g*128 + idx];
    __hip_atomic_fetch_add(p, 1u, __ATOMIC_RELAXED, __HIP_MEMORY_SCOPE_AGENT);
    while (__hip_atomic_load(p, __ATOMIC_RELAXED, __HIP_MEMORY_SCOPE_AGENT) < (unsigned)PACE_TGT)
      __builtin_amdgcn_s_sleep(1);
  }
  __syncthreads();
}

// A fragment: row = m*16 + (lane&15); k = kc + (lane>>4)*4 + j (+16 for j>=4)
template<int STRIDE>
__device__ __forceinline__ f16x8 load_afrag(const f16* buf, int m, int kc, int lane){
  const f16* p = buf + (m*16 + (lane&15))*STRIDE + kc + ((lane>>4)<<2);
  f16x4 lo = *(const f16x4*)p;
  f16x4 hi = *(const f16x4*)(p+16);
  return __builtin_shufflevector(lo, hi, 0,1,2,3,4,5,6,7);
}

// acc[mt][g] accumulates gate g (ntile g*8+wv) for rows mt*16..mt*16+15
__device__ __forceinline__ void init_acc(f32x4 acc[2][4],
                                         const float* __restrict__ bias, int wv, int lane){
#pragma unroll
  for (int i=0;i<4;++i){
    float bv = bias[i*128 + wv*16 + (lane&15)];
    f32x4 b4 = {bv,bv,bv,bv};
    acc[0][i]=b4; acc[1][i]=b4;
  }
}

// gates[32 rows][4 gates x 16 units] += [A(SPLIT kt, HS, hi) | C(rest, SB,
// hi + optional lo product)] * B_hi     (ntile for gate i = i*8 + wv)
template<int KT, int SPLIT, int SB, bool CLO>
__device__ __forceinline__ void gemm2(f32x4 acc[2][4],
    const f16x8* __restrict__ Bp,
    const f16* __restrict__ Ah,
    const f16* __restrict__ Ch, const f16* __restrict__ Cl,
    int wv, int lane)
{
  f16x8 Bc[4], Bn[4];
#pragma unroll
  for (int i=0;i<4;++i) Bc[i] = Bp[(i*8 + wv)*64 + lane];
#pragma unroll
  for (int kt=0; kt<KT; ++kt){
    if (kt+1 < KT){
#pragma unroll
      for (int i=0;i<4;++i) Bn[i] = Bp[((kt+1)*32 + i*8 + wv)*64 + lane];
    }
    if (kt < SPLIT){
      int kc = kt*32;
      f16x8 a0h = load_afrag<HS>(Ah, 0, kc, lane);
      f16x8 a1h = load_afrag<HS>(Ah, 1, kc, lane);
#pragma unroll
      for (int i=0;i<4;++i){
        acc[0][i] = MFMA16(a0h, Bc[i], acc[0][i]);
        acc[1][i] = MFMA16(a1h, Bc[i], acc[1][i]);
      }
    } else {
      int kc = (kt-SPLIT)*32;
      f16x8 c0h = load_afrag<SB>(Ch, 0, kc, lane);
      f16x8 c1h = load_afrag<SB>(Ch, 1, kc, lane);
#pragma unroll
      for (int i=0;i<4;++i){
        acc[0][i] = MFMA16(c0h, Bc[i], acc[0][i]);
        acc[1][i] = MFMA16(c1h, Bc[i], acc[1][i]);
      }
      if (CLO){
        f16x8 c0l = load_afrag<SB>(Cl, 0, kc, lane);
        f16x8 c1l = load_afrag<SB>(Cl, 1, kc, lane);
#pragma unroll
        for (int i=0;i<4;++i){
          acc[0][i] = MFMA16(c0l, Bc[i], acc[0][i]);
          acc[1][i] = MFMA16(c1l, Bc[i], acc[1][i]);
        }
      }
    }
#pragma unroll
    for (int i=0;i<4;++i) Bc[i] = Bn[i];
  }
}

// transpose-free update: acc[mt][0..3][r] = (i,f,g,o) of (row mt*16+rg+r,
// unit wv*16+(lane&15)); C/D layout col=lane&15, row=(lane>>4)*4+r [m89]
__device__ __forceinline__ void lstm_update_m(f32x4 acc[2][4], float cr[2][4],
    f16* __restrict__ Dh, int wv, int lane)
{
  const int unit = wv*16 + (lane&15);
  const int rg   = (lane>>4)<<2;
#pragma unroll
  for (int mt=0;mt<2;++mt)
#pragma unroll
  for (int r=0;r<4;++r){
    float iv = fsig(acc[mt][0][r]);
    float fv = fsig(acc[mt][1][r]);
    float gv = ftanh(acc[mt][2][r]);
    float ov = fsig(acc[mt][3][r]);
    float cn = fv*cr[mt][r] + iv*gv;
    cr[mt][r] = cn;
    float h = ov*ftanh(cn);
    Dh[(mt*16 + rg + r)*HS + unit] = (f16)h;
  }
}

__global__ void __launch_bounds__(512, 2)
lstm_main(const float* __restrict__ hist, float* __restrict__ ws,
          float* __restrict__ out)
{
  const f16* wh = (const f16*)ws;
  const float* wf = ws + FOFF;
  unsigned* bar = (unsigned*)(ws + FOFF + BAR_F);
  const f16x8* BE0 = (const f16x8*)(wh + HOFF_E0);
  const f16x8* BE1 = (const f16x8*)(wh + HOFF_E1);
  const f16x8* BD0 = (const f16x8*)(wh + HOFF_D0);
  const f16x8* BD1 = (const f16x8*)(wh + HOFF_D1);
  const f16x8* BH  = (const f16x8*)(wh + HOFF_H);

  __shared__ __align__(16) f16 smem[L_HALVES];
  __shared__ __align__(16) float o1buf[32*O1S];

  const int tid  = threadIdx.x;
  const int wv   = tid >> 6;
  const int lane = tid & 63;
  const int b0   = blockIdx.x * BM;
  const int g    = blockIdx.x & 7;
  const int lidx = lane & 15;

  for (int i = tid; i < L_HALVES; i += 512) smem[i] = (f16)0.f;   // zero h+x bufs
  float c0r[2][4] = {{0,0,0,0},{0,0,0,0}};
  float c1r[2][4] = {{0,0,0,0},{0,0,0,0}};
  f32x4 acc[2][4];

  const int lr = tid/6, ld = tid - (tid/6)*6;   // hist loader (tid<192)

  __syncthreads();   // zeros visible before x(0) seed
  if (tid < 192){    // x(0) -> x buf parity 1 (t=0 reads c^1 = 1)
    float v = hist[(b0+lr)*768 + ld];
    f16 hv = (f16)v;
    smem[L_XH + XBUF + lr*XS + ld] = hv;
    smem[L_XL + XBUF + lr*XS + ld] = (f16)(v - (float)hv);
  }
  __syncthreads();

  // ------- encoder: 128 steps, 1 barrier/step + pace every 2nd step -------
  for (int t=0; t<128; ++t){
    const int c  = t & 1;            // write parity
    const int hw = c*HBUF, hr = (c^1)*HBUF;
    const int xw = c*XBUF, xr = (c^1)*XBUF;

    // P1: gemm0(t) [h0 hi, x hi+lo] + x(t+1) load + upd0 -> h0[c]
    init_acc(acc, wf + FB_E0, wv, lane);
    gemm2<5,4,XS,true>(acc, BE0,
                       smem + L_H0 + hr,
                       smem + L_XH + xr, smem + L_XL + xr, wv, lane);
    if (t < 127 && tid < 192){
      float v = hist[(b0+lr)*768 + (t+1)*6 + ld];
      f16 hv = (f16)v;
      smem[L_XH + xw + lr*XS + ld] = hv;
      smem[L_XL + xw + lr*XS + ld] = (f16)(v - (float)hv);
    }
    lstm_update_m(acc, c0r, smem + L_H0 + hw, wv, lane);
    __syncthreads();

    // P2: gemm1(t) reads h0[c], h1[c^1] (hi only); upd1 -> h1[c]
    init_acc(acc, wf + FB_E1, wv, lane);
    gemm2<8,4,HS,false>(acc, BE1,
                        smem + L_H0 + hw,
                        smem + L_H1 + hr, smem + L_H1 + hr, wv, lane);
    lstm_update_m(acc, c1r, smem + L_H1 + hw, wv, lane);
    // no step-end barrier: P2(t) and P1(t+1) are conflict-free (dbl-buffered)
    if (t & 1) grid_pace(bar, t>>1, g, tid);   // lockstep every 2 steps
  }

  __syncthreads();   // close t=127 P2 writes before decoder seed
  // decoder seed: x = hist[:, -1, :2] -> x buf parity 1
  if (tid < 64){
    int r = tid>>1, j = tid&1;
    float v = hist[(b0+r)*768 + 762 + j];
    f16 hv = (f16)v;
    smem[L_XH + XBUF + r*XS + j] = hv;
    smem[L_XL + XBUF + r*XS + j] = (f16)(v - (float)hv);
  }
  __syncthreads();

  // ------- decoder: 125 steps, pace every 2nd step -------
  for (int t=0; t<125; ++t){
    const int c  = t & 1;
    const int hw = c*HBUF, hr = (c^1)*HBUF;
    const int xw = c*XBUF, xr = (c^1)*XBUF;

    // P1: gemm0 + upd0 -> h0[c]
    init_acc(acc, wf + FB_D0, wv, lane);
    gemm2<5,4,XS,true>(acc, BD0,
                       smem + L_H0 + hr,
                       smem + L_XH + xr, smem + L_XL + xr, wv, lane);
    lstm_update_m(acc, c0r, smem + L_H0 + hw, wv, lane);
    __syncthreads();

    // P2: gemm1 + upd1 -> h1[c]
    init_acc(acc, wf + FB_D1, wv, lane);
    gemm2<8,4,HS,false>(acc, BD1,
                        smem + L_H0 + hw,
                        smem + L_H1 + hr, smem + L_H1 + hr, wv, lane);
    lstm_update_m(acc, c1r, smem + L_H1 + hw, wv, lane);
    __syncthreads();

    // P3: head1: relu(h1(t) @ W1^T + b1) -> o1 (hi only)
    {
      const f16* h1wH = smem + L_H1 + hw;
      float bH1 = wf[FB_H1 + wv*16 + lidx];
      f32x4 ha0 = {bH1,bH1,bH1,bH1};
      f32x4 ha1 = ha0;
#pragma unroll
      for (int kt=0;kt<4;++kt){
        f16x8 Wc = BH[(kt*8 + wv)*64 + lane];
        int kc = kt*32;
        f16x8 a0h = load_afrag<HS>(h1wH, 0, kc, lane);
        f16x8 a1h = load_afrag<HS>(h1wH, 1, kc, lane);
        ha0 = MFMA16(a0h, Wc, ha0);
        ha1 = MFMA16(a1h, Wc, ha1);
      }
#pragma unroll
      for (int r=0;r<4;++r){
        float v0 = ha0[r]; v0 = v0 > 0.f ? v0 : 0.f;
        float v1 = ha1[r]; v1 = v1 > 0.f ? v1 : 0.f;
        int rr = ((lane>>4)<<2) + r;
        o1buf[rr*O1S      + wv*16 + lidx] = v0;
        o1buf[(16+rr)*O1S + wv*16 + lidx] = v1;
      }
    }
    __syncthreads();

    // P4: head2, conflict-free parallel (512 thr = 32r x 2j x 8s) + feedback
    {
      const int r = tid >> 4;          // 0..31
      const int j = (tid >> 3) & 1;
      const int s = tid & 7;
      const float* op = o1buf + r*O1S;
      float pa=0.f, pb=0.f;
#pragma unroll
      for (int i=0;i<16;i+=2){
        int k0 = i*8 + s, k1 = (i+1)*8 + s;
        pa = fmaf(op[k0], wf[FB_W2 + k0*2 + j], pa);
        pb = fmaf(op[k1], wf[FB_W2 + k1*2 + j], pb);
      }
      float p = pa + pb;
      p += __shfl_xor(p, 1);
      p += __shfl_xor(p, 2);
      p += __shfl_xor(p, 4);
      if (s == 0){
        float pred = wf[FB_B2 + j] + p;
        out[(b0+r)*250 + t*2 + j] = pred;
        f16 ph = (f16)pred;
        smem[L_XH + xw + r*XS + j] = ph;
        smem[L_XL + xw + r*XS + j] = (f16)(pred - (float)ph);
      }
    }
    // step-end sync required (P4 x-write feeds next P1): pace every 2nd step
    if (t & 1) grid_pace(bar, 64 + (t>>1), g, tid);
    else       __syncthreads();
  }
}

// ---------------------------------------------------------------------------
// setup: pack B-hi weights, gate-major columns (col = gate*128 + unit =
// ORIGINAL row index -> orow = col identity). k-fragment map unchanged.
// ---------------------------------------------------------------------------
__global__ void setup_kernel(
    const float* __restrict__ eWih0, const float* __restrict__ eWhh0,
    const float* __restrict__ ebih0, const float* __restrict__ ebhh0,
    const float* __restrict__ eWih1, const float* __restrict__ eWhh1,
    const float* __restrict__ ebih1, const float* __restrict__ ebhh1,
    const float* __restrict__ dWih0, const float* __restrict__ dWhh0,
    const float* __restrict__ dbih0, const float* __restrict__ dbhh0,
    const float* __restrict__ dWih1, const float* __restrict__ dWhh1,
    const float* __restrict__ dbih1, const float* __restrict__ dbhh1,
    const float* __restrict__ W1, const float* __restrict__ b1,
    const float* __restrict__ W2, const float* __restrict__ b2,
    float* __restrict__ ws)
{
  int i = blockIdx.x*256 + threadIdx.x;
  if (i < H_TOTAL){
    f16* whp = (f16*)ws;
    const float *Wa, *Wb; int ka, kb, off; bool head = false;
    if      (i < HOFF_E1){ off=HOFF_E0; Wa=eWhh0; ka=128; Wb=eWih0; kb=6; }
    else if (i < HOFF_D0){ off=HOFF_E1; Wa=eWih1; ka=128; Wb=eWhh1; kb=128; }
    else if (i < HOFF_D1){ off=HOFF_D0; Wa=dWhh0; ka=128; Wb=dWih0; kb=2; }
    else if (i < HOFF_H) { off=HOFF_D1; Wa=dWih1; ka=128; Wb=dWhh1; kb=128; }
    else                 { off=HOFF_H;  Wa=W1; ka=128; Wb=W1; kb=0; head=true; }
    int local = i - off;
    int j     = local & 7;
    int lane  = (local>>3) & 63;
    int nk    = local >> 9;
    int NTl   = head ? 8 : 32;
    int n     = nk % NTl;
    int kt    = nk / NTl;
    int col   = n*16 + (lane&15);
    int koff  = ((j>>2)<<4) + ((lane>>4)<<2) + (j&3);
    int kin   = kt*32 + koff;
    float val;
    if (head){
      val = (kin < 128) ? W1[col*128 + kin] : 0.f;
    } else {
      val = (kin < ka) ? Wa[col*ka + kin]
          : ((kin < ka+kb) ? Wb[col*kb + (kin-ka)] : 0.f);
    }
    whp[i] = (f16)val;
  } else if (i < H_TOTAL + F_TOTAL){
    int f = i - H_TOTAL;
    float* wfp = ws + FOFF;
    if (f < 2048){
      int layer = f >> 9, c = f & 511;
      const float *bi, *bh;
      if      (layer==0){ bi=ebih0; bh=ebhh0; }
      else if (layer==1){ bi=ebih1; bh=ebhh1; }
      else if (layer==2){ bi=dbih0; bh=dbhh0; }
      else              { bi=dbih1; bh=dbhh1; }
      wfp[f] = bi[c] + bh[c];
    } else if (f < 2176){
      wfp[f] = b1[f-2048];
    } else if (f < 2432){
      int k = (f-2176)>>1, j = (f-2176)&1;
      wfp[f] = W2[j*128 + k];
    } else {
      wfp[f] = b2[f-2432];
    }
  }
}

extern "C" void kernel_launch(void* const* d_in, const int* in_sizes, int n_in,
                              void* d_out, int out_size, void* d_ws, size_t ws_size,
                              hipStream_t stream)
{
  const float* hist = (const float*)d_in[0];
  float* ws = (float*)d_ws;

  // zero the pacing-barrier counters (capture-safe async memset)
  (void)hipMemsetAsync((char*)d_ws + (size_t)(FOFF + BAR_F)*4, 0, BAR_BYTES, stream);

  int total = H_TOTAL + F_TOTAL;
  setup_kernel<<<(total + 255)/256, 256, 0, stream>>>(
      (const float*)d_in[1],  (const float*)d_in[2],
      (const float*)d_in[3],  (const float*)d_in[4],
      (const float*)d_in[5],  (const float*)d_in[6],
      (const float*)d_in[7],  (const float*)d_in[8],
      (const float*)d_in[9],  (const float*)d_in[10],
      (const float*)d_in[11], (const float*)d_in[12],
      (const float*)d_in[13], (const float*)d_in[14],
      (const float*)d_in[15], (const float*)d_in[16],
      (const float*)d_in[17], (const float*)d_in[18],
      (const float*)d_in[19], (const float*)d_in[20],
      ws);

  lstm_main<<<NBLK, 512, 0, stream>>>(hist, ws, (float*)d_out);
}